// Round 9
// baseline (292.639 us; speedup 1.0000x reference)
//
#include <hip/hip_runtime.h>
#include <math.h>

#define L_ 8
#define D_ 128
#define B_ 8192
#define P_ 28
#define ALPHA_ 0.1f

typedef __attribute__((ext_vector_type(8))) short bf16x8;
typedef __attribute__((ext_vector_type(4))) float f32x4;
union BF8 { int4 i; bf16x8 h; short s[8]; };

__device__ __forceinline__ short f2bf(float f) {
    unsigned u = __float_as_uint(f);
    unsigned r = (u + 0x7fffu + ((u >> 16) & 1u)) >> 16;   // RNE
    return (short)(r & 0xffffu);
}
__device__ __forceinline__ unsigned rne2(float a, float b) {
    unsigned ua = __float_as_uint(a); ua += 0x7fffu + ((ua >> 16) & 1u);
    unsigned ub = __float_as_uint(b); ub += 0x7fffu + ((ub >> 16) & 1u);
    return __builtin_amdgcn_perm(ub, ua, 0x07060302);      // {b_hi16, a_hi16} -> mem order a,b
}
__device__ __forceinline__ unsigned cvt_pk_bf16(float lo, float hi) {
    unsigned r;
    asm("v_cvt_pk_bf16_f32 %0, %1, %2" : "=v"(r) : "v"(lo), "v"(hi));
    return r;
}
__device__ __forceinline__ float fast_tanh(float x) {
    float e = exp2f(x * 2.885390081777927f);               // e^{2x}
    return 1.f - 2.f * __builtin_amdgcn_rcpf(e + 1.f);
}

// ---------------------------------------------------------------------------
// W transpose -> bf16 fragment layout for DIRECT per-wave global A-frag reads.
// Per (p,ch) 64KB: byte offset kb*8192 + ct*1024 + m*64 + q*16, holding W^T
// element (k=kb*32+q*8+e, hidden=ch*128+ct*16+m). A wave's 64 lanes cover one
// ct-tile's 1KB contiguously (perfect coalescing, zero dup).
// ---------------------------------------------------------------------------
__global__ void transpose_w(const float* __restrict__ W1, const float* __restrict__ W2,
                            short* __restrict__ T1, short* __restrict__ T2) {
    const float* W = blockIdx.y ? W2 : W1;
    short* T = blockIdx.y ? T2 : T1;
    const int p = blockIdx.x >> 3, kb = blockIdx.x & 7;
    __shared__ float tile[32][260];
    const int tid = threadIdx.x;
    for (int s = tid; s < 8192; s += 256) {
        int kk = s >> 8, n = s & 255;
        tile[kk][n] = W[((size_t)p * 256 + kb * 32 + kk) * 256 + n];
    }
    __syncthreads();
    const int n = tid;
    const int ch = n >> 7, ct = (n >> 4) & 7, mm = n & 15;
    const size_t sb = (((size_t)p * 2 + ch) * 64 + kb * 8) * 512;   // kb-slice base (shorts)
    short tmp[32];
#pragma unroll
    for (int kk = 0; kk < 32; ++kk) tmp[kk] = f2bf(tile[kk][n]);
#pragma unroll
    for (int c4 = 0; c4 < 4; ++c4) {
        BF8 u;
#pragma unroll
        for (int e = 0; e < 8; ++e) u.s[e] = tmp[c4 * 8 + e];
        const int byt = ct * 1024 + mm * 64 + c4 * 16;              // linear
        *(int4*)&T[sb + (byt >> 1)] = u.i;
    }
}

// ---------------------------------------------------------------------------
// S (f32) -> bf16 B-fragment layout, computed ONCE. Per 16-row group rg:
// 2048 shorts, elem(row,k) at (k/8 *16 + row%16)*8 + k%8.
// ---------------------------------------------------------------------------
__global__ void prep_s16(const float* __restrict__ S, short* __restrict__ S16) {
    __shared__ __align__(16) short ls[8192];            // 16 KB bounce, bank-swizzled
    const int t = threadIdx.x;
    const size_t base = (size_t)blockIdx.x * 8192;      // 64 rows x 128
#pragma unroll
    for (int rr = 0; rr < 8; ++rr) {
        const int idx = rr * 1024 + t * 4;
        const float4 v = *(const float4*)&S[base + idx];
        const int row = idx >> 7, col = idx & 127;
        const int rgl = row >> 4, mr = row & 15, kq = col >> 3, c4 = (col >> 2) & 1;
        const unsigned w0 = rne2(v.x, v.y), w1 = rne2(v.z, v.w);
        const int byt = (rgl * 4096 + kq * 256 + mr * 16 + c4 * 8) ^ ((kq & 7) << 4);
        *(uint2*)((char*)ls + byt) = (uint2){w0, w1};
    }
    __syncthreads();
#pragma unroll
    for (int r = 0; r < 4; ++r) {
        const int un = r * 256 + t;                      // 16-B unit
        const int kq = (un >> 4) & 15;
        const int byt = (un * 16) ^ ((kq & 7) << 4);
        *(int4*)&S16[base + (size_t)un * 8] = *(const int4*)((const char*)ls + byt);
    }
}

// ---------------------------------------------------------------------------
// Fused per-layer kernel, block = (layer k, 128 rows), 512 threads / 8 waves.
// vs round 8 (198 us): u's 32 VGPRs eliminated. Round-8 total was 84 arch +
// 64 acc = 148 regs/wave -> 129-256 occupancy band -> only 8 waves/CU (22.7%
// measured), pure latency-bound. The propagation recurrence
//   u_{t+1} = 0.9 u_t + 0.1 e_t,  e_t = st_t (G2_t + b2_t)
// unrolls to u_7 = 0.9^7 u_0 + 0.1 sum_t w_t e_t (w_t = 0.9^{6-t}) and the
// weighted sum is folded INTO the G2 accumulator C (invariant s_t*C = E_t,
// s_t = w_t*st_t): at iter t, C <- C * (0.9 st_{t-1}/st_t) + b2_t, then G2's
// MFMAs accumulate. Epilogue: OUT = 0.9^7 * S + 0.1*st_6*C (S read only
// there). Live set ~119 <= 128 -> 16 waves/CU. Mathematically identical;
// rounding deltas ~1e-6 << bf16-dominated absmax.
// ---------------------------------------------------------------------------
__launch_bounds__(512, 3)
__global__ void fused(const float* __restrict__ S, const float* __restrict__ ES,
                      const float* __restrict__ b1, const float* __restrict__ b2,
                      const short* __restrict__ S16, const short* __restrict__ T1,
                      const short* __restrict__ T2, float* __restrict__ OUT) {
    __shared__ __align__(16) short Hs[32768];     // 64 KB: full h tile (128 x 256), frag layout
    const int k = blockIdx.x, rb = blockIdx.y;
    const int tid = threadIdx.x, lane = tid & 63, w = tid >> 6;
    const int wr = w >> 2, wc = w & 3;
    const int m = lane & 15, q = lane >> 4;
    char* const hsb = (char*)Hs;
    const int afo = wc * 1024 + m * 32 + q * 8;   // A-frag lane offset (shorts); +at*512

    const size_t srow = (size_t)k * B_ + rb * 128;

    f32x4 acc2[2][4];                              // persistent: carries E_t/s_t
    float st_prev = 1.f;

    for (int it = 0; it < 7; ++it) {
        const int mp = it + (it >= k ? 1 : 0);     // partner (ascending = global pair order)
        const int li = k < mp ? k : mp;
        const int lj = k < mp ? mp : k;
        const int p  = li * 7 - ((li * (li - 1)) >> 1) + (lj - li - 1);
        const int side = (k == li) ? 0 : 1;
        const float es = ES[li * L_ + lj];
        const float st = 1.f / (1.f + expf(-es));
        const float ratio = 0.9f * st_prev / st;

        // fold previous E into this iter's scale; add b2_t (C-in for G2 MFMAs)
#pragma unroll
        for (int at = 0; at < 2; ++at) {
            const f32x4 bv = *(const f32x4*)&b2[p * 256 + side * 128 + wc * 32 + at * 16 + q * 4];
#pragma unroll
            for (int nt = 0; nt < 4; ++nt)
#pragma unroll
                for (int r = 0; r < 4; ++r)
                    acc2[at][nt][r] = (it == 0) ? bv[r] : acc2[at][nt][r] * ratio + bv[r];
        }
        st_prev = st;

        // B-frag bases for this block's row-slab (layer li / lj)
        const short* biL = S16 + ((size_t)li * 512 + rb * 8 + wr * 4) * 2048 + (q * 16 + m) * 8;
        const short* biJ = S16 + ((size_t)lj * 512 + rb * 8 + wr * 4) * 2048 + (q * 16 + m) * 8;

        // ============ G1: both hidden halves -> full H in LDS (no barriers) ====
        for (int hh = 0; hh < 2; ++hh) {
            const short* wA = T1 + ((size_t)(p * 2 + hh) << 15) + afo;
            f32x4 acc1[2][4];
#pragma unroll
            for (int at = 0; at < 2; ++at) {
                const f32x4 bv = *(const f32x4*)&b1[p * 256 + hh * 128 + wc * 32 + at * 16 + q * 4];
#pragma unroll
                for (int nt = 0; nt < 4; ++nt) acc1[at][nt] = bv;
            }
            bf16x8 Bc[4], Bn[4];
#pragma unroll
            for (int nt = 0; nt < 4; ++nt) Bc[nt] = *(const bf16x8*)(biL + nt * 2048);
#pragma unroll
            for (int kb = 0; kb < 8; ++kb) {
                if (kb < 7) {                       // prefetch next kb's B-frags
                    const int kn = kb + 1;
                    const short* spn = ((kn < 4) ? biL : biJ) + (kn & 3) * 512;
#pragma unroll
                    for (int nt = 0; nt < 4; ++nt) Bn[nt] = *(const bf16x8*)(spn + nt * 2048);
                }
                const bf16x8 A0 = *(const bf16x8*)(wA + kb * 4096);
                const bf16x8 A1 = *(const bf16x8*)(wA + kb * 4096 + 512);
#pragma unroll
                for (int nt = 0; nt < 4; ++nt) {
                    acc1[0][nt] = __builtin_amdgcn_mfma_f32_16x16x32_bf16(A0, Bc[nt], acc1[0][nt], 0, 0, 0);
                    acc1[1][nt] = __builtin_amdgcn_mfma_f32_16x16x32_bf16(A1, Bc[nt], acc1[1][nt], 0, 0, 0);
                }
#pragma unroll
                for (int nt = 0; nt < 4; ++nt) Bc[nt] = Bn[nt];
            }
            // tanh -> bf16 -> Hs in FRAGMENT layout (conflict-free 8B stores):
            // hidden = hh*128 + (wc*2+at)*16 + q*4 + rr, row = wr*64 + nt*16 + m
            // byte = (wr*4+nt)*8192 + (hidden/8)*256 + m*16 + (q&1)*8
#pragma unroll
            for (int at = 0; at < 2; ++at) {
                const int cb = (hh * 16 + wc * 4 + at * 2 + (q >> 1)) * 256 + m * 16 + (q & 1) * 8;
#pragma unroll
                for (int nt = 0; nt < 4; ++nt) {
                    const float v0 = fast_tanh(acc1[at][nt][0]);
                    const float v1 = fast_tanh(acc1[at][nt][1]);
                    const float v2 = fast_tanh(acc1[at][nt][2]);
                    const float v3 = fast_tanh(acc1[at][nt][3]);
                    const unsigned p0 = cvt_pk_bf16(v0, v1);
                    const unsigned p1 = cvt_pk_bf16(v2, v3);
                    *(uint2*)(hsb + (wr * 4 + nt) * 8192 + cb) = (uint2){p0, p1};
                }
            }
        }
        __syncthreads();                           // full H visible to all waves

        // ============ G2 over full K=256, accumulating into persistent C =======
        const short* wA2 = T2 + ((size_t)(p * 2 + side) << 15) + afo;
#pragma unroll
        for (int kb = 0; kb < 8; ++kb) {
            const bf16x8 A0 = *(const bf16x8*)(wA2 + kb * 4096);
            const bf16x8 A1 = *(const bf16x8*)(wA2 + kb * 4096 + 512);
            const int hc = (kb * 4 + q) * 256 + m * 16;      // fragment-layout read
#pragma unroll
            for (int nt = 0; nt < 4; ++nt) {
                const bf16x8 Hf = *(const bf16x8*)(hsb + (wr * 4 + nt) * 8192 + hc);
                acc2[0][nt] = __builtin_amdgcn_mfma_f32_16x16x32_bf16(A0, Hf, acc2[0][nt], 0, 0, 0);
                acc2[1][nt] = __builtin_amdgcn_mfma_f32_16x16x32_bf16(A1, Hf, acc2[1][nt], 0, 0, 0);
            }
        }
        __syncthreads();                           // all G2 reads done before next tanh-store
    }

    // epilogue: u_7 = 0.9^7 * u0 + 0.1 * st_6 * C  (u0 = S read only here)
    const float fin = 0.1f * st_prev;
#pragma unroll
    for (int nt = 0; nt < 4; ++nt)
#pragma unroll
        for (int at = 0; at < 2; ++at) {
            const size_t off = (srow + wr * 64 + nt * 16 + m) * D_ + wc * 32 + at * 16 + q * 4;
            const f32x4 u0 = *(const f32x4*)&S[off];
            f32x4 o;
#pragma unroll
            for (int r = 0; r < 4; ++r)
                o[r] = 0.4782969f * u0[r] + fin * acc2[at][nt][r];
            *(f32x4*)&OUT[off] = o;
        }
}

// measures analytically constant (lam1 == 1 after normalize):
// (127+127-255)*1e-12*(-ln 1e-12) = -2.7631021115928547e-11
__global__ void fill_meas(float* __restrict__ M) {
    int t = blockIdx.x * 256 + threadIdx.x;
    if (t < P_ * B_) M[t] = -2.7631021115928547e-11f;
}

extern "C" void kernel_launch(void* const* d_in, const int* in_sizes, int n_in,
                              void* d_out, int out_size, void* d_ws, size_t ws_size,
                              hipStream_t stream) {
    const float* S  = (const float*)d_in[0];
    const float* ES = (const float*)d_in[1];
    const float* W1 = (const float*)d_in[2];
    const float* b1 = (const float*)d_in[3];
    const float* W2 = (const float*)d_in[4];
    const float* b2 = (const float*)d_in[5];

    short* S16 = (short*)d_ws;                           // 8*8192*128 shorts = 16.8 MB
    short* T1  = S16 + (size_t)L_ * B_ * D_;             // 56*32768 shorts = 3.67 MB
    short* T2  = T1 + (size_t)P_ * 2 * 32768;            // 3.67 MB  (total 24.1 MB)

    float* OUT  = (float*)d_out;                         // updated [L,B,D]
    float* MEAS = OUT + (size_t)L_ * B_ * D_;            // measures [P,B]

    transpose_w<<<dim3(P_ * 8, 2), 256, 0, stream>>>(W1, W2, T1, T2);
    prep_s16<<<dim3(1024), 256, 0, stream>>>(S, S16);
    fused<<<dim3(8, 64), 512, 0, stream>>>(S, ES, b1, b2, S16, T1, T2, OUT);
    fill_meas<<<dim3(896), 256, 0, stream>>>(MEAS);
}

// Round 10
// 280.385 us; speedup vs baseline: 1.0437x; 1.0437x over previous
//
#include <hip/hip_runtime.h>
#include <math.h>

#define L_ 8
#define D_ 128
#define B_ 8192
#define P_ 28
#define ALPHA_ 0.1f

typedef __attribute__((ext_vector_type(8))) short bf16x8;
typedef __attribute__((ext_vector_type(4))) float f32x4;
union BF8 { int4 i; bf16x8 h; short s[8]; };

__device__ __forceinline__ short f2bf(float f) {
    unsigned u = __float_as_uint(f);
    unsigned r = (u + 0x7fffu + ((u >> 16) & 1u)) >> 16;   // RNE
    return (short)(r & 0xffffu);
}
__device__ __forceinline__ unsigned rne2(float a, float b) {
    unsigned ua = __float_as_uint(a); ua += 0x7fffu + ((ua >> 16) & 1u);
    unsigned ub = __float_as_uint(b); ub += 0x7fffu + ((ub >> 16) & 1u);
    return __builtin_amdgcn_perm(ub, ua, 0x07060302);      // {b_hi16, a_hi16} -> mem order a,b
}
__device__ __forceinline__ unsigned cvt_pk_bf16(float lo, float hi) {
    unsigned r;
    asm("v_cvt_pk_bf16_f32 %0, %1, %2" : "=v"(r) : "v"(lo), "v"(hi));
    return r;
}
__device__ __forceinline__ float fast_tanh(float x) {
    float e = exp2f(x * 2.885390081777927f);               // e^{2x}
    return 1.f - 2.f * __builtin_amdgcn_rcpf(e + 1.f);
}

// ---------------------------------------------------------------------------
// W transpose -> bf16 fragment layout for DIRECT per-wave global A-frag reads.
// Per (p,ch) 64KB: byte offset kb*8192 + ct*1024 + m*64 + q*16, holding W^T
// element (k=kb*32+q*8+e, hidden=ch*128+ct*16+m). A wave's 64 lanes cover one
// ct-tile's 1KB contiguously (perfect coalescing, zero dup).
// ---------------------------------------------------------------------------
__global__ void transpose_w(const float* __restrict__ W1, const float* __restrict__ W2,
                            short* __restrict__ T1, short* __restrict__ T2) {
    const float* W = blockIdx.y ? W2 : W1;
    short* T = blockIdx.y ? T2 : T1;
    const int p = blockIdx.x >> 3, kb = blockIdx.x & 7;
    __shared__ float tile[32][260];
    const int tid = threadIdx.x;
    for (int s = tid; s < 8192; s += 256) {
        int kk = s >> 8, n = s & 255;
        tile[kk][n] = W[((size_t)p * 256 + kb * 32 + kk) * 256 + n];
    }
    __syncthreads();
    const int n = tid;
    const int ch = n >> 7, ct = (n >> 4) & 7, mm = n & 15;
    const size_t sb = (((size_t)p * 2 + ch) * 64 + kb * 8) * 512;   // kb-slice base (shorts)
    short tmp[32];
#pragma unroll
    for (int kk = 0; kk < 32; ++kk) tmp[kk] = f2bf(tile[kk][n]);
#pragma unroll
    for (int c4 = 0; c4 < 4; ++c4) {
        BF8 u;
#pragma unroll
        for (int e = 0; e < 8; ++e) u.s[e] = tmp[c4 * 8 + e];
        const int byt = ct * 1024 + mm * 64 + c4 * 16;              // linear
        *(int4*)&T[sb + (byt >> 1)] = u.i;
    }
}

// ---------------------------------------------------------------------------
// S (f32) -> bf16 B-fragment layout, computed ONCE. Per 16-row group rg:
// 2048 shorts, elem(row,k) at (k/8 *16 + row%16)*8 + k%8.
// ---------------------------------------------------------------------------
__global__ void prep_s16(const float* __restrict__ S, short* __restrict__ S16) {
    __shared__ __align__(16) short ls[8192];            // 16 KB bounce, bank-swizzled
    const int t = threadIdx.x;
    const size_t base = (size_t)blockIdx.x * 8192;      // 64 rows x 128
#pragma unroll
    for (int rr = 0; rr < 8; ++rr) {
        const int idx = rr * 1024 + t * 4;
        const float4 v = *(const float4*)&S[base + idx];
        const int row = idx >> 7, col = idx & 127;
        const int rgl = row >> 4, mr = row & 15, kq = col >> 3, c4 = (col >> 2) & 1;
        const unsigned w0 = rne2(v.x, v.y), w1 = rne2(v.z, v.w);
        const int byt = (rgl * 4096 + kq * 256 + mr * 16 + c4 * 8) ^ ((kq & 7) << 4);
        *(uint2*)((char*)ls + byt) = (uint2){w0, w1};
    }
    __syncthreads();
#pragma unroll
    for (int r = 0; r < 4; ++r) {
        const int un = r * 256 + t;                      // 16-B unit
        const int kq = (un >> 4) & 15;
        const int byt = (un * 16) ^ ((kq & 7) << 4);
        *(int4*)&S16[base + (size_t)un * 8] = *(const int4*)((const char*)ls + byt);
    }
}

// ---------------------------------------------------------------------------
// Fused per-layer kernel, block = (layer k, 128 rows), 512 threads / 8 waves.
// vs round 9 (211 us, 148 regs -> 8 waves/CU): the register PEAK, not u, was
// the wall. Loaded-data that must stay live: Bc 16 + Bn 16 + A 8 + acc 64
// = 104, plus ~44 addr/temps = 148 -> rounds to 256-granule -> 2 waves/SIMD.
// This round: DROP the Bn software prefetch (16 regs) and pin
// __launch_bounds__(512,4) (cap 128). Must-hold loaded data is now 88;
// addresses are rematerializable, so the allocator fits without spilling
// (round 6 spilled under this bound because u+Bn+Bc=120 was unspillable).
// ILP traded for TLP: 16 waves/CU (4/SIMD) hide the G1 B-load latency by
// wave-switching instead of register prefetch.
// ---------------------------------------------------------------------------
__launch_bounds__(512, 4)
__global__ void fused(const float* __restrict__ S, const float* __restrict__ ES,
                      const float* __restrict__ b1, const float* __restrict__ b2,
                      const short* __restrict__ S16, const short* __restrict__ T1,
                      const short* __restrict__ T2, float* __restrict__ OUT) {
    __shared__ __align__(16) short Hs[32768];     // 64 KB: full h tile (128 x 256), frag layout
    const int k = blockIdx.x, rb = blockIdx.y;
    const int tid = threadIdx.x, lane = tid & 63, w = tid >> 6;
    const int wr = w >> 2, wc = w & 3;
    const int m = lane & 15, q = lane >> 4;
    char* const hsb = (char*)Hs;
    const int afo = wc * 1024 + m * 32 + q * 8;   // A-frag lane offset (shorts); +at*512

    const size_t srow = (size_t)k * B_ + rb * 128;

    f32x4 acc2[2][4];                              // persistent: carries E_t/s_t
    float st_prev = 1.f;

    for (int it = 0; it < 7; ++it) {
        const int mp = it + (it >= k ? 1 : 0);     // partner (ascending = global pair order)
        const int li = k < mp ? k : mp;
        const int lj = k < mp ? mp : k;
        const int p  = li * 7 - ((li * (li - 1)) >> 1) + (lj - li - 1);
        const int side = (k == li) ? 0 : 1;
        const float es = ES[li * L_ + lj];
        const float st = 1.f / (1.f + expf(-es));
        const float ratio = 0.9f * st_prev / st;

        // fold previous E into this iter's scale; add b2_t (C-in for G2 MFMAs)
#pragma unroll
        for (int at = 0; at < 2; ++at) {
            const f32x4 bv = *(const f32x4*)&b2[p * 256 + side * 128 + wc * 32 + at * 16 + q * 4];
#pragma unroll
            for (int nt = 0; nt < 4; ++nt)
#pragma unroll
                for (int r = 0; r < 4; ++r)
                    acc2[at][nt][r] = (it == 0) ? bv[r] : acc2[at][nt][r] * ratio + bv[r];
        }
        st_prev = st;

        // B-frag base for layer li; lj's base is a uniform (scalar) delta away
        const short* biL = S16 + ((size_t)li * 512 + rb * 8 + wr * 4) * 2048 + (q * 16 + m) * 8;
        const size_t dJ = (size_t)(lj - li) * 512 * 2048;

        // ============ G1: both hidden halves -> full H in LDS (no barriers) ====
        for (int hh = 0; hh < 2; ++hh) {
            const short* wA = T1 + ((size_t)(p * 2 + hh) << 15) + afo;
            f32x4 acc1[2][4];
#pragma unroll
            for (int at = 0; at < 2; ++at) {
                const f32x4 bv = *(const f32x4*)&b1[p * 256 + hh * 128 + wc * 32 + at * 16 + q * 4];
#pragma unroll
                for (int nt = 0; nt < 4; ++nt) acc1[at][nt] = bv;
            }
#pragma unroll
            for (int kb = 0; kb < 8; ++kb) {
                const short* sp = biL + ((kb < 4) ? 0 : dJ) + (kb & 3) * 512;
                const bf16x8 A0 = *(const bf16x8*)(wA + kb * 4096);
                const bf16x8 A1 = *(const bf16x8*)(wA + kb * 4096 + 512);
#pragma unroll
                for (int nt = 0; nt < 4; ++nt) {
                    const bf16x8 Bf = *(const bf16x8*)(sp + nt * 2048);
                    acc1[0][nt] = __builtin_amdgcn_mfma_f32_16x16x32_bf16(A0, Bf, acc1[0][nt], 0, 0, 0);
                    acc1[1][nt] = __builtin_amdgcn_mfma_f32_16x16x32_bf16(A1, Bf, acc1[1][nt], 0, 0, 0);
                }
            }
            // tanh -> bf16 -> Hs in FRAGMENT layout (conflict-free 8B stores):
            // hidden = hh*128 + (wc*2+at)*16 + q*4 + rr, row = wr*64 + nt*16 + m
            // byte = (wr*4+nt)*8192 + (hidden/8)*256 + m*16 + (q&1)*8
#pragma unroll
            for (int at = 0; at < 2; ++at) {
                const int cb = (hh * 16 + wc * 4 + at * 2 + (q >> 1)) * 256 + m * 16 + (q & 1) * 8;
#pragma unroll
                for (int nt = 0; nt < 4; ++nt) {
                    const float v0 = fast_tanh(acc1[at][nt][0]);
                    const float v1 = fast_tanh(acc1[at][nt][1]);
                    const float v2 = fast_tanh(acc1[at][nt][2]);
                    const float v3 = fast_tanh(acc1[at][nt][3]);
                    const unsigned p0 = cvt_pk_bf16(v0, v1);
                    const unsigned p1 = cvt_pk_bf16(v2, v3);
                    *(uint2*)(hsb + (wr * 4 + nt) * 8192 + cb) = (uint2){p0, p1};
                }
            }
        }
        __syncthreads();                           // full H visible to all waves

        // ============ G2 over full K=256, accumulating into persistent C =======
        const short* wA2 = T2 + ((size_t)(p * 2 + side) << 15) + afo;
#pragma unroll
        for (int kb = 0; kb < 8; ++kb) {
            const bf16x8 A0 = *(const bf16x8*)(wA2 + kb * 4096);
            const bf16x8 A1 = *(const bf16x8*)(wA2 + kb * 4096 + 512);
            const int hc = (kb * 4 + q) * 256 + m * 16;      // fragment-layout read
#pragma unroll
            for (int nt = 0; nt < 4; ++nt) {
                const bf16x8 Hf = *(const bf16x8*)(hsb + (wr * 4 + nt) * 8192 + hc);
                acc2[0][nt] = __builtin_amdgcn_mfma_f32_16x16x32_bf16(A0, Hf, acc2[0][nt], 0, 0, 0);
                acc2[1][nt] = __builtin_amdgcn_mfma_f32_16x16x32_bf16(A1, Hf, acc2[1][nt], 0, 0, 0);
            }
        }
        __syncthreads();                           // all G2 reads done before next tanh-store
    }

    // epilogue: u_7 = 0.9^7 * u0 + 0.1 * st_6 * C  (u0 = S read only here)
    const float fin = 0.1f * st_prev;
#pragma unroll
    for (int nt = 0; nt < 4; ++nt)
#pragma unroll
        for (int at = 0; at < 2; ++at) {
            const size_t off = (srow + wr * 64 + nt * 16 + m) * D_ + wc * 32 + at * 16 + q * 4;
            const f32x4 u0 = *(const f32x4*)&S[off];
            f32x4 o;
#pragma unroll
            for (int r = 0; r < 4; ++r)
                o[r] = 0.4782969f * u0[r] + fin * acc2[at][nt][r];
            *(f32x4*)&OUT[off] = o;
        }
}

// measures analytically constant (lam1 == 1 after normalize):
// (127+127-255)*1e-12*(-ln 1e-12) = -2.7631021115928547e-11
__global__ void fill_meas(float* __restrict__ M) {
    int t = blockIdx.x * 256 + threadIdx.x;
    if (t < P_ * B_) M[t] = -2.7631021115928547e-11f;
}

extern "C" void kernel_launch(void* const* d_in, const int* in_sizes, int n_in,
                              void* d_out, int out_size, void* d_ws, size_t ws_size,
                              hipStream_t stream) {
    const float* S  = (const float*)d_in[0];
    const float* ES = (const float*)d_in[1];
    const float* W1 = (const float*)d_in[2];
    const float* b1 = (const float*)d_in[3];
    const float* W2 = (const float*)d_in[4];
    const float* b2 = (const float*)d_in[5];

    short* S16 = (short*)d_ws;                           // 8*8192*128 shorts = 16.8 MB
    short* T1  = S16 + (size_t)L_ * B_ * D_;             // 56*32768 shorts = 3.67 MB
    short* T2  = T1 + (size_t)P_ * 2 * 32768;            // 3.67 MB  (total 24.1 MB)

    float* OUT  = (float*)d_out;                         // updated [L,B,D]
    float* MEAS = OUT + (size_t)L_ * B_ * D_;            // measures [P,B]

    transpose_w<<<dim3(P_ * 8, 2), 256, 0, stream>>>(W1, W2, T1, T2);
    prep_s16<<<dim3(1024), 256, 0, stream>>>(S, S16);
    fused<<<dim3(8, 64), 512, 0, stream>>>(S, ES, b1, b2, S16, T1, T2, OUT);
    fill_meas<<<dim3(896), 256, 0, stream>>>(MEAS);
}

// Round 11
// 256.853 us; speedup vs baseline: 1.1393x; 1.0916x over previous
//
#include <hip/hip_runtime.h>
#include <math.h>

#define L_ 8
#define D_ 128
#define B_ 8192
#define P_ 28
#define ALPHA_ 0.1f

typedef __attribute__((ext_vector_type(8))) short bf16x8;
typedef __attribute__((ext_vector_type(4))) float f32x4;
union BF8 { int4 i; bf16x8 h; short s[8]; };

__device__ __forceinline__ short f2bf(float f) {
    unsigned u = __float_as_uint(f);
    unsigned r = (u + 0x7fffu + ((u >> 16) & 1u)) >> 16;   // RNE
    return (short)(r & 0xffffu);
}
__device__ __forceinline__ unsigned rne2(float a, float b) {
    unsigned ua = __float_as_uint(a); ua += 0x7fffu + ((ua >> 16) & 1u);
    unsigned ub = __float_as_uint(b); ub += 0x7fffu + ((ub >> 16) & 1u);
    return __builtin_amdgcn_perm(ub, ua, 0x07060302);      // {b_hi16, a_hi16} -> mem order a,b
}
__device__ __forceinline__ unsigned cvt_pk_bf16(float lo, float hi) {
    unsigned r;
    asm("v_cvt_pk_bf16_f32 %0, %1, %2" : "=v"(r) : "v"(lo), "v"(hi));
    return r;
}
__device__ __forceinline__ float fast_tanh(float x) {
    float e = exp2f(x * 2.885390081777927f);               // e^{2x}
    return 1.f - 2.f * __builtin_amdgcn_rcpf(e + 1.f);
}

typedef const unsigned int __attribute__((address_space(1)))* gas_t;
typedef unsigned int __attribute__((address_space(3)))* las_t;

// ---------------------------------------------------------------------------
// W transpose -> bf16 fragment layout for DIRECT per-wave global A-frag reads.
// Per (p,ch) 64KB: byte offset kb*8192 + ct*1024 + m*64 + q*16, holding W^T
// element (k=kb*32+q*8+e, hidden=ch*128+ct*16+m).
// ---------------------------------------------------------------------------
__global__ void transpose_w(const float* __restrict__ W1, const float* __restrict__ W2,
                            short* __restrict__ T1, short* __restrict__ T2) {
    const float* W = blockIdx.y ? W2 : W1;
    short* T = blockIdx.y ? T2 : T1;
    const int p = blockIdx.x >> 3, kb = blockIdx.x & 7;
    __shared__ float tile[32][260];
    const int tid = threadIdx.x;
    for (int s = tid; s < 8192; s += 256) {
        int kk = s >> 8, n = s & 255;
        tile[kk][n] = W[((size_t)p * 256 + kb * 32 + kk) * 256 + n];
    }
    __syncthreads();
    const int n = tid;
    const int ch = n >> 7, ct = (n >> 4) & 7, mm = n & 15;
    const size_t sb = (((size_t)p * 2 + ch) * 64 + kb * 8) * 512;   // kb-slice base (shorts)
    short tmp[32];
#pragma unroll
    for (int kk = 0; kk < 32; ++kk) tmp[kk] = f2bf(tile[kk][n]);
#pragma unroll
    for (int c4 = 0; c4 < 4; ++c4) {
        BF8 u;
#pragma unroll
        for (int e = 0; e < 8; ++e) u.s[e] = tmp[c4 * 8 + e];
        const int byt = ct * 1024 + mm * 64 + c4 * 16;              // linear
        *(int4*)&T[sb + (byt >> 1)] = u.i;
    }
}

// ---------------------------------------------------------------------------
// S (f32) -> bf16 B-fragment layout, computed ONCE. Per 16-row group rg:
// 2048 shorts, elem(row,k) at (k/8 *16 + row%16)*8 + k%8.
// ---------------------------------------------------------------------------
__global__ void prep_s16(const float* __restrict__ S, short* __restrict__ S16) {
    __shared__ __align__(16) short ls[8192];            // 16 KB bounce, bank-swizzled
    const int t = threadIdx.x;
    const size_t base = (size_t)blockIdx.x * 8192;      // 64 rows x 128
#pragma unroll
    for (int rr = 0; rr < 8; ++rr) {
        const int idx = rr * 1024 + t * 4;
        const float4 v = *(const float4*)&S[base + idx];
        const int row = idx >> 7, col = idx & 127;
        const int rgl = row >> 4, mr = row & 15, kq = col >> 3, c4 = (col >> 2) & 1;
        const unsigned w0 = rne2(v.x, v.y), w1 = rne2(v.z, v.w);
        const int byt = (rgl * 4096 + kq * 256 + mr * 16 + c4 * 8) ^ ((kq & 7) << 4);
        *(uint2*)((char*)ls + byt) = (uint2){w0, w1};
    }
    __syncthreads();
#pragma unroll
    for (int r = 0; r < 4; ++r) {
        const int un = r * 256 + t;                      // 16-B unit
        const int kq = (un >> 4) & 15;
        const int byt = (un * 16) ^ ((kq & 7) << 4);
        *(int4*)&S16[base + (size_t)un * 8] = *(const int4*)((const char*)ls + byt);
    }
}

// stage one 16 KB S16 slab (contiguous, already fragment-layout) into LDS.
// Zero VGPR cost (direct-to-LDS DMA); 4 calls/wave x 4 waves x 1 KB = 16 KB.
__device__ __forceinline__ void stage16k(const short* __restrict__ src, short* dst,
                                         int w, int lane) {
#pragma unroll
    for (int r = 0; r < 4; ++r) {
        const int u0 = (w * 4 + r) * 64;                 // 16-B units
        __builtin_amdgcn_global_load_lds((gas_t)(const void*)(src + (size_t)(u0 + lane) * 8),
                                         (las_t)(void*)(dst + u0 * 8), 16, 0, 0);
    }
}

// ---------------------------------------------------------------------------
// Fused per-layer kernel, block = (layer k, 64 rows), 256 threads / 4 waves.
// vs round 10 (193 us, 42% occ): doubling TLP bought nothing -> per-wave ILP
// was the wall (0 free arch VGPRs at the 128 cap -> loads serialized, every
// one a ~250cyc L2 round-trip). This round buys load DEPTH with LDS DMA
// (zero VGPR): B-operands staged via global_load_lds -- own-layer slab (16KB,
// iter-invariant) staged ONCE; partner slab (16KB) staged per iter, issued
// right after its last-consumer barrier so the DMA hides under G2. G2 split
// per hidden-half (K-order unchanged -> bit-identical) shrinks Hh to 16KB:
// 48KB/block -> 3 blocks/CU = 12 waves/CU with 3-block barrier diversity.
// __syncthreads() drains vmcnt anyway, so the stage-wait is free (exactly one
// useful drain/iter -- NOT round-3's 24). B-reads: conflict-free ds_read_b128.
// ---------------------------------------------------------------------------
__launch_bounds__(256, 4)
__global__ void fused(const float* __restrict__ S, const float* __restrict__ ES,
                      const float* __restrict__ b1, const float* __restrict__ b2,
                      const short* __restrict__ S16, const short* __restrict__ T1,
                      const short* __restrict__ T2, float* __restrict__ OUT) {
    __shared__ __align__(16) short Sown[8192];    // 16 KB own-layer B-tile (resident)
    __shared__ __align__(16) short Spar[8192];    // 16 KB partner B-tile (per iter)
    __shared__ __align__(16) short Hh[8192];      // 16 KB H half-tile (per hh)
    const int k = blockIdx.x, rb = blockIdx.y;
    const int tid = threadIdx.x, lane = tid & 63, wc = tid >> 6;
    const int m = lane & 15, q = lane >> 4;
    char* const hsb = (char*)Hh;
    const int afo = wc * 1024 + m * 32 + q * 8;   // A-frag lane offset (shorts); +at*512
    const int bfo = (q * 16 + m) * 8;             // B-frag lane offset within rg/kbl block

    const size_t srow = (size_t)k * B_ + rb * 64;

    // initial stages: own slab (iter-invariant) + partner slab for it=0
    stage16k(S16 + ((size_t)k * 512 + rb * 4) * 2048, Sown, wc, lane);
    {
        const int mp0 = (0 >= k) ? 1 : 0;
        stage16k(S16 + ((size_t)mp0 * 512 + rb * 4) * 2048, Spar, wc, lane);
    }

    f32x4 acc2[2][4];                              // persistent: carries E_t/s_t
    float st_prev = 1.f;

    for (int it = 0; it < 7; ++it) {
        const int mp = it + (it >= k ? 1 : 0);     // partner (ascending = global pair order)
        const int li = k < mp ? k : mp;
        const int lj = k < mp ? mp : k;
        const int p  = li * 7 - ((li * (li - 1)) >> 1) + (lj - li - 1);
        const int side = (k == li) ? 0 : 1;
        const float es = ES[li * L_ + lj];
        const float st = 1.f / (1.f + expf(-es));
        const float ratio = 0.9f * st_prev / st;

        // fold previous E into this iter's scale; add b2_t (VALU, hides DMA)
#pragma unroll
        for (int at = 0; at < 2; ++at) {
            const f32x4 bv = *(const f32x4*)&b2[p * 256 + side * 128 + wc * 32 + at * 16 + q * 4];
#pragma unroll
            for (int nt = 0; nt < 4; ++nt)
#pragma unroll
                for (int r = 0; r < 4; ++r)
                    acc2[at][nt][r] = (it == 0) ? bv[r] : acc2[at][nt][r] * ratio + bv[r];
        }
        st_prev = st;

        __syncthreads();                           // B1: Spar (DMA) ready + Hh free

        for (int hh = 0; hh < 2; ++hh) {
            // ---- G1 half hh: K 0..255, kb<4 = s_li, kb>=4 = s_lj ---------------
            const short* wA = T1 + ((size_t)(p * 2 + hh) << 15) + afo;
            f32x4 acc1[2][4];
#pragma unroll
            for (int at = 0; at < 2; ++at) {
                const f32x4 bv = *(const f32x4*)&b1[p * 256 + hh * 128 + wc * 32 + at * 16 + q * 4];
#pragma unroll
                for (int nt = 0; nt < 4; ++nt) acc1[at][nt] = bv;
            }
#pragma unroll
            for (int kb = 0; kb < 8; ++kb) {
                // source slab: (kb<4 -> layer li), own layer k == li iff side==0
                const short* lsrc = ((kb < 4) == (side == 0)) ? Sown : Spar;
                const short* sp = lsrc + (kb & 3) * 512 + bfo;
                const bf16x8 A0 = *(const bf16x8*)(wA + kb * 4096);
                const bf16x8 A1 = *(const bf16x8*)(wA + kb * 4096 + 512);
#pragma unroll
                for (int nt = 0; nt < 4; ++nt) {
                    const bf16x8 Bf = *(const bf16x8*)(sp + nt * 2048);
                    acc1[0][nt] = __builtin_amdgcn_mfma_f32_16x16x32_bf16(A0, Bf, acc1[0][nt], 0, 0, 0);
                    acc1[1][nt] = __builtin_amdgcn_mfma_f32_16x16x32_bf16(A1, Bf, acc1[1][nt], 0, 0, 0);
                }
            }
            // tanh -> bf16 -> Hh fragment layout (conflict-free 8B stores)
            // kd = hidden-within-half/8 = wc*4+at*2+(q>>1); byte = nt*4096+kd*256+m*16+(q&1)*8
#pragma unroll
            for (int at = 0; at < 2; ++at) {
                const int cb = (wc * 4 + at * 2 + (q >> 1)) * 256 + m * 16 + (q & 1) * 8;
#pragma unroll
                for (int nt = 0; nt < 4; ++nt) {
                    const float v0 = fast_tanh(acc1[at][nt][0]);
                    const float v1 = fast_tanh(acc1[at][nt][1]);
                    const float v2 = fast_tanh(acc1[at][nt][2]);
                    const float v3 = fast_tanh(acc1[at][nt][3]);
                    const unsigned p0 = cvt_pk_bf16(v0, v1);
                    const unsigned p1 = cvt_pk_bf16(v2, v3);
                    *(uint2*)(hsb + nt * 4096 + cb) = (uint2){p0, p1};
                }
            }
            __syncthreads();                       // B2/B4: Hh half ready

            // after last Spar read of this iter (hh==1 kb-loop done, confirmed by
            // the barrier above): issue next iter's partner stage -> hides under G2
            if (hh == 1 && it < 6) {
                const int mp2 = (it + 1) + ((it + 1) >= k ? 1 : 0);
                stage16k(S16 + ((size_t)mp2 * 512 + rb * 4) * 2048, Spar, wc, lane);
            }

            // ---- G2 chunk: K = hh*128..hh*128+127, accumulate into persistent C --
            const short* wA2 = T2 + ((size_t)(p * 2 + side) << 15) + afo;
#pragma unroll
            for (int kc = 0; kc < 4; ++kc) {
                const int kb = hh * 4 + kc;
                const bf16x8 A0 = *(const bf16x8*)(wA2 + kb * 4096);
                const bf16x8 A1 = *(const bf16x8*)(wA2 + kb * 4096 + 512);
                const int hc = (kc * 4 + q) * 256 + m * 16;
#pragma unroll
                for (int nt = 0; nt < 4; ++nt) {
                    const bf16x8 Hf = *(const bf16x8*)(hsb + nt * 4096 + hc);
                    acc2[0][nt] = __builtin_amdgcn_mfma_f32_16x16x32_bf16(A0, Hf, acc2[0][nt], 0, 0, 0);
                    acc2[1][nt] = __builtin_amdgcn_mfma_f32_16x16x32_bf16(A1, Hf, acc2[1][nt], 0, 0, 0);
                }
            }
            if (hh == 0) __syncthreads();          // B3: Hh consumed (hh1 reuses it)
            // (hh==1: next iter's B1 separates G2 reads from the next Hh writes)
        }
    }

    // epilogue: u_7 = 0.9^7 * u0 + 0.1 * st_6 * C  (u0 = S read only here)
    const float fin = 0.1f * st_prev;
#pragma unroll
    for (int nt = 0; nt < 4; ++nt)
#pragma unroll
        for (int at = 0; at < 2; ++at) {
            const size_t off = (srow + nt * 16 + m) * D_ + wc * 32 + at * 16 + q * 4;
            const f32x4 u0 = *(const f32x4*)&S[off];
            f32x4 o;
#pragma unroll
            for (int r = 0; r < 4; ++r)
                o[r] = 0.4782969f * u0[r] + fin * acc2[at][nt][r];
            *(f32x4*)&OUT[off] = o;
        }
}

// measures analytically constant (lam1 == 1 after normalize):
// (127+127-255)*1e-12*(-ln 1e-12) = -2.7631021115928547e-11
__global__ void fill_meas(float* __restrict__ M) {
    int t = blockIdx.x * 256 + threadIdx.x;
    if (t < P_ * B_) M[t] = -2.7631021115928547e-11f;
}

extern "C" void kernel_launch(void* const* d_in, const int* in_sizes, int n_in,
                              void* d_out, int out_size, void* d_ws, size_t ws_size,
                              hipStream_t stream) {
    const float* S  = (const float*)d_in[0];
    const float* ES = (const float*)d_in[1];
    const float* W1 = (const float*)d_in[2];
    const float* b1 = (const float*)d_in[3];
    const float* W2 = (const float*)d_in[4];
    const float* b2 = (const float*)d_in[5];

    short* S16 = (short*)d_ws;                           // 8*8192*128 shorts = 16.8 MB
    short* T1  = S16 + (size_t)L_ * B_ * D_;             // 56*32768 shorts = 3.67 MB
    short* T2  = T1 + (size_t)P_ * 2 * 32768;            // 3.67 MB  (total 24.1 MB)

    float* OUT  = (float*)d_out;                         // updated [L,B,D]
    float* MEAS = OUT + (size_t)L_ * B_ * D_;            // measures [P,B]

    transpose_w<<<dim3(P_ * 8, 2), 256, 0, stream>>>(W1, W2, T1, T2);
    prep_s16<<<dim3(1024), 256, 0, stream>>>(S, S16);
    fused<<<dim3(8, 128), 256, 0, stream>>>(S, ES, b1, b2, S16, T1, T2, OUT);
    fill_meas<<<dim3(896), 256, 0, stream>>>(MEAS);
}